// Round 1
// baseline (833.124 us; speedup 1.0000x reference)
//
#include <hip/hip_runtime.h>
#include <math.h>

typedef __bf16 bf16;
typedef __bf16 bf16x8 __attribute__((ext_vector_type(8)));
typedef float  f32x4  __attribute__((ext_vector_type(4)));

#define MFMA16(a,b,c) __builtin_amdgcn_mfma_f32_16x16x32_bf16((a),(b),(c),0,0,0)

#define B_SZ 4096
#define T_SZ 200
#define D_SZ 128
#define U_SZ 128
#define ACHUNK 4
#define AROWS 16    // batch rows per augru block (full M=16 MFMA tiles)
#define ATTB 8      // batch elems per attn block

__device__ __forceinline__ float frcp_(float x) { return __builtin_amdgcn_rcpf(x); }
__device__ __forceinline__ float fsig(float x)  { return frcp_(1.0f + __expf(-x)); }
__device__ __forceinline__ float ftanh_(float x){ return 1.0f - 2.0f * frcp_(1.0f + __expf(2.0f * x)); }
// dice with moving_mean=0, moving_var=1: x_norm == x (1/sqrt(1+1e-9) rounds to 1.0f)
__device__ __forceinline__ float dicef(float x, float alpha) {
    float p = fsig(x);
    return alpha * (1.0f - p) * x + p * x;
}
// Barrier that waits ONLY lgkmcnt (LDS visibility). Register-destined global
// loads stay in flight across it (no vmcnt(0) drain like __syncthreads emits);
// compiler still inserts counted vmcnt before the registers are consumed.
// All call sites are in wave-uniform control flow.
__device__ __forceinline__ void bar_lgkm() {
    asm volatile("s_waitcnt lgkmcnt(0)\n\ts_barrier" ::: "memory");
}

// ---------------------------------------------------------------------------
// Prep: blocks 0..255 compute bias1[b,n] = q[b]@(W1a+W1c) via MFMA (16 rows each).
// Block 256 converts combined W1' -> bf16 [n][k] (k<128: W1b-W1c; k>=128: W1d)
// and W2^T -> bf16 [n][k].
// ---------------------------------------------------------------------------
__global__ __launch_bounds__(256) void prep_kernel(
    const float* __restrict__ Q,    // [B,128]
    const float* __restrict__ W1,   // [512,64]
    const float* __restrict__ W2,   // [64,16]
    float* __restrict__ BIAS,       // [B,64]
    bf16*  __restrict__ W1P,        // [64][256]
    bf16*  __restrict__ W2T)        // [16][64]
{
    const int tid = threadIdx.x;
    if (blockIdx.x == 256) {
        #pragma unroll 4
        for (int it = 0; it < 64; ++it) {
            int idx = it * 256 + tid;
            int k = idx >> 6;           // 0..255
            int n = idx & 63;
            float v;
            if (k < 128) v = W1[(128 + k) * 64 + n] - W1[(256 + k) * 64 + n];
            else         v = W1[(384 + (k - 128)) * 64 + n];
            W1P[n * 256 + k] = (bf16)v;
        }
        #pragma unroll
        for (int it = 0; it < 4; ++it) {
            int idx = it * 256 + tid; int k = idx >> 4; int n = idx & 15;
            W2T[n * 64 + k] = (bf16)W2[k * 16 + n];
        }
        return;
    }
    const int b0   = blockIdx.x * 16;
    const int lane = tid & 63;
    const int w    = tid >> 6;
    const int quad = lane >> 4;
    const int l15  = lane & 15;

    bf16x8 a[4];
    #pragma unroll
    for (int kk = 0; kk < 4; ++kk) {
        const float* p = Q + (long)(b0 + l15) * D_SZ + kk * 32 + quad * 8;
        float4 x0 = ((const float4*)p)[0];
        float4 x1 = ((const float4*)p)[1];
        float xv[8] = {x0.x, x0.y, x0.z, x0.w, x1.x, x1.y, x1.z, x1.w};
        #pragma unroll
        for (int j = 0; j < 8; ++j) a[kk][j] = (bf16)xv[j];
    }
    const int n = w * 16 + l15;
    f32x4 acc = {};
    #pragma unroll
    for (int kk = 0; kk < 4; ++kk) {
        bf16x8 bf;
        #pragma unroll
        for (int j = 0; j < 8; ++j) {
            int k = kk * 32 + quad * 8 + j;
            bf[j] = (bf16)(W1[k * 64 + n] + W1[(256 + k) * 64 + n]);
        }
        acc = MFMA16(a[kk], bf, acc);
    }
    #pragma unroll
    for (int i = 0; i < 4; ++i)
        BIAS[(long)(b0 + quad * 4 + i) * 64 + n] = acc[i];
}

// ---------------------------------------------------------------------------
// Kernel 1: attention scores. ATTB=8 batch elems per block, flattened
// (bi, mt) tile loop with software-pipelined X loads; ONE barrier total.
// (unchanged this round — isolating the augru restructure)
// ---------------------------------------------------------------------------
__global__ __launch_bounds__(256) void attn_kernel(
    const float* __restrict__ X,    // [B,T,D]
    const float* __restrict__ Q,    // [B,D]
    const int*   __restrict__ LEN,  // [B,1]
    const float* __restrict__ A1,   // [64]
    const float* __restrict__ A2,   // [16]
    const float* __restrict__ W3,   // [16,1]
    const float* __restrict__ BIAS, // [B,64]
    const bf16*  __restrict__ W1P,  // [64][256]
    const bf16*  __restrict__ W2T,  // [16][64]
    float* __restrict__ ATT)        // [B,T]
{
    __shared__ bf16  H1s[64][72];       // wave-private 16-row dice(h1) buffer
    __shared__ float qf[ATTB][128];
    __shared__ float bias_s[ATTB][64];
    __shared__ float al1[64];
    __shared__ float al2[16];
    __shared__ float w3s[16];
    __shared__ int   lens[ATTB];

    const int tid  = threadIdx.x;
    const int lane = tid & 63;
    const int w    = tid >> 6;
    const int quad = lane >> 4;
    const int l15  = lane & 15;
    const long b0  = (long)blockIdx.x * ATTB;

    for (int i = tid; i < ATTB * 128; i += 256) qf[i >> 7][i & 127] = Q[b0 * 128 + i];
    for (int i = tid; i < ATTB * 64;  i += 256) bias_s[i >> 6][i & 63] = BIAS[b0 * 64 + i];
    if (tid < 64) al1[tid] = A1[tid];
    if (tid < 16) { al2[tid] = A2[tid]; w3s[tid] = W3[tid]; }
    if (tid < ATTB) lens[tid] = LEN[b0 + tid];

    // register B-fragments straight from prepped global bf16 (L2-hot)
    bf16x8 b1[4][8];
    #pragma unroll
    for (int nt = 0; nt < 4; ++nt)
        #pragma unroll
        for (int kk = 0; kk < 8; ++kk)
            b1[nt][kk] = *(const bf16x8*)(W1P + (nt * 16 + l15) * 256 + kk * 32 + quad * 8);
    bf16x8 b2[2];
    #pragma unroll
    for (int kk = 0; kk < 2; ++kk)
        b2[kk] = *(const bf16x8*)(W2T + l15 * 64 + kk * 32 + quad * 8);
    __syncthreads();

    const int NT = 13 * ATTB;
    float4 fb[8];
    auto issue = [&](int g) {
        int bi = g / 13, mt = g - bi * 13;
        int row = mt * 16 + l15;
        int rc  = row < T_SZ ? row : (T_SZ - 1);
        const float* xp = X + ((b0 + bi) * T_SZ + rc) * D_SZ;
        #pragma unroll
        for (int kc = 0; kc < 4; ++kc) {
            const float* p = xp + kc * 32 + quad * 8;
            fb[kc * 2]     = ((const float4*)p)[0];
            fb[kc * 2 + 1] = ((const float4*)p)[1];
        }
    };
    auto convert = [&](int g, bf16x8* axd, bf16x8* aqd) {
        int bi = g / 13;
        #pragma unroll
        for (int kc = 0; kc < 4; ++kc) {
            float4 xa = fb[kc * 2], xb = fb[kc * 2 + 1];
            float xv[8] = {xa.x, xa.y, xa.z, xa.w, xb.x, xb.y, xb.z, xb.w};
            const float* qp = &qf[bi][kc * 32 + quad * 8];
            #pragma unroll
            for (int j = 0; j < 8; ++j) {
                axd[kc][j] = (bf16)xv[j];
                aqd[kc][j] = (bf16)(xv[j] * qp[j]);
            }
        }
    };

    bf16x8 axc[4], aqc[4];
    issue(w);
    convert(w, axc, aqc);

    for (int g = w; g < NT; g += 4) {
        const int gn = g + 4;
        if (gn < NT) issue(gn);            // loads in flight over MFMAs below

        f32x4 acc[4] = {};
        #pragma unroll
        for (int kc = 0; kc < 4; ++kc)
            #pragma unroll
            for (int nt = 0; nt < 4; ++nt) {
                acc[nt] = MFMA16(axc[kc], b1[nt][kc],     acc[nt]);
                acc[nt] = MFMA16(aqc[kc], b1[nt][kc + 4], acc[nt]);
            }

        const int bi = g / 13, mt = g - bi * 13;
        const int m0 = mt * 16;
        #pragma unroll
        for (int nt = 0; nt < 4; ++nt) {
            int n = nt * 16 + l15;
            float bia = bias_s[bi][n]; float al = al1[n];
            #pragma unroll
            for (int i = 0; i < 4; ++i) {
                float v = acc[nt][i] + bia;
                H1s[w * 16 + quad * 4 + i][n] = (bf16)dicef(v, al);
            }
        }
        f32x4 acc2 = {};
        #pragma unroll
        for (int kk = 0; kk < 2; ++kk) {
            bf16x8 a2 = *(const bf16x8*)&H1s[w * 16 + l15][kk * 32 + quad * 8];
            acc2 = MFMA16(a2, b2[kk], acc2);
        }
        {
            float al = al2[l15]; float w3 = w3s[l15];
            float s[4];
            #pragma unroll
            for (int i = 0; i < 4; ++i) s[i] = dicef(acc2[i], al) * w3;
            #pragma unroll
            for (int i = 0; i < 4; ++i) {
                s[i] += __shfl_xor(s[i], 1, 64);
                s[i] += __shfl_xor(s[i], 2, 64);
                s[i] += __shfl_xor(s[i], 4, 64);
                s[i] += __shfl_xor(s[i], 8, 64);
            }
            if (l15 == 0) {
                int len = lens[bi];
                #pragma unroll
                for (int i = 0; i < 4; ++i) {
                    int t = m0 + quad * 4 + i;
                    if (t < T_SZ)
                        ATT[(b0 + bi) * T_SZ + t] = (t < len) ? fsig(s[i]) : 0.0f;
                }
            }
        }
        if (gn < NT) convert(gn, axc, aqc);
    }
}

// ---------------------------------------------------------------------------
// Kernel 2: AUGRU, software-pipelined scan.
//  - lgkm-only barriers: global X/ATT prefetch spans the whole chunk
//    (no vmcnt(0) drain at the 8 per-chunk barriers).
//  - x-part MFMAs of step t+1 (12, h-independent) issued inside phase-2 of
//    step t: they hide the RHb LDS round trip + tanh chain. Chunk boundary
//    peeled (xparts of s=0 run after the chunk's last barrier).
//  - u = fsig(pu) hoisted to phase-1; phase-2 critical path is only
//    ar-read -> 4 MFMA -> tanh -> fma.
//  - next-chunk commit spread across the four phase-2s (slice s writes
//    Xs[buf^1][s]; last read of that buffer was >=1 barrier earlier),
//    removing the former per-chunk 9th barrier.
// ---------------------------------------------------------------------------
__global__ __launch_bounds__(512) void augru_kernel(
    const float* __restrict__ X,    // [B,T,D]
    const float* __restrict__ ATT,  // [B,T]
    const float* __restrict__ WU,   // [256,128]
    const float* __restrict__ WR,
    const float* __restrict__ WC,
    float* __restrict__ OUT)        // [B,128]
{
    __shared__ bf16  Xs[2][ACHUNK][16][136];
    __shared__ float As[2][ACHUNK][16];
    __shared__ bf16  Hb[16][136];
    __shared__ bf16  RHb[16][136];

    const int tid  = threadIdx.x;
    const int lane = tid & 63;
    const int w    = tid >> 6;      // 0..7
    const int quad = lane >> 4;
    const int l15  = lane & 15;
    const int b0   = blockIdx.x * AROWS;
    const int n    = w * 16 + l15;  // this lane's output column

    for (int i = tid; i < 16 * 136; i += 512) { ((bf16*)Hb)[i] = (bf16)0.f; ((bf16*)RHb)[i] = (bf16)0.f; }

    // per-wave weight slice: Wf[gate][part(0=x,1=h)][kk], 24 frags = 96 VGPR
    bf16x8 Wf[3][2][4];
    {
        const float* Wg[3] = {WU, WR, WC};
        #pragma unroll
        for (int g = 0; g < 3; ++g)
            #pragma unroll
            for (int p = 0; p < 2; ++p)
                #pragma unroll
                for (int kk = 0; kk < 4; ++kk) {
                    #pragma unroll
                    for (int i = 0; i < 8; ++i) {
                        int k = p * 128 + kk * 32 + quad * 8 + i;
                        Wf[g][p][kk][i] = (bf16)Wg[g][k * 128 + n];
                    }
                }
    }

    float h[4] = {0.f, 0.f, 0.f, 0.f};   // lane-private hidden state

    float4 pf[4];
    float  pa = 0.f;
    auto issue_loads = [&](int c) {
        #pragma unroll
        for (int it = 0; it < 4; ++it) {
            int gidx = it * 512 + tid;
            int c4 = gidx & 31;
            int pair = gidx >> 5;
            int r = pair & 15;
            int s = pair >> 4;
            pf[it] = *(const float4*)(X + ((long)(b0 + r) * T_SZ + (c * ACHUNK + s)) * D_SZ + c4 * 4);
        }
        if (tid < ACHUNK * 16) {
            int r = tid & 15; int s = tid >> 4;
            pa = ATT[(long)(b0 + r) * T_SZ + c * ACHUNK + s];
        }
    };
    // commit slice `it` == time-slot `it` of the next chunk (gidx>>9 == it)
    auto commit_part = [&](int buf, int it) {
        int gidx = it * 512 + tid;
        int c4 = gidx & 31;
        int pair = gidx >> 5;
        int r = pair & 15;
        int s = pair >> 4;
        bf16* dst = &Xs[buf][s][r][c4 * 4];
        float4 v = pf[it];
        dst[0] = (bf16)v.x; dst[1] = (bf16)v.y; dst[2] = (bf16)v.z; dst[3] = (bf16)v.w;
        if (it == 0 && tid < ACHUNK * 16) {
            int r2 = tid & 15; int s2 = tid >> 4;
            As[buf][s2][r2] = pa;
        }
    };
    // h-independent x-parts of one time step (12 MFMAs, 3 independent chains)
    auto xparts = [&](int buf, int s, f32x4& pr_, f32x4& pu_, f32x4& pc_) {
        f32x4 r0 = {}, u0 = {}, c0 = {};
        #pragma unroll
        for (int kk = 0; kk < 4; ++kk) {
            bf16x8 ax = *(const bf16x8*)&Xs[buf][s][l15][kk * 32 + quad * 8];
            r0 = MFMA16(ax, Wf[1][0][kk], r0);
            u0 = MFMA16(ax, Wf[0][0][kk], u0);
            c0 = MFMA16(ax, Wf[2][0][kk], c0);
        }
        pr_ = r0; pu_ = u0; pc_ = c0;
    };

    issue_loads(0);
    #pragma unroll
    for (int it = 0; it < 4; ++it) commit_part(0, it);
    bar_lgkm();

    f32x4 pr, pu, pc;
    xparts(0, 0, pr, pu, pc);

    const int NCH = T_SZ / ACHUNK;   // 50
    for (int c = 0; c < NCH; ++c) {
        const int buf = c & 1;
        if (c + 1 < NCH) issue_loads(c + 1);   // spans all 8 chunk barriers

        #pragma unroll
        for (int s = 0; s < ACHUNK; ++s) {
            // ---- phase 1: r,u h-parts (critical: pr -> fsig -> RHb) ----
            bf16x8 ah[4];
            #pragma unroll
            for (int kk = 0; kk < 4; ++kk)
                ah[kk] = *(const bf16x8*)&Hb[l15][kk * 32 + quad * 8];
            #pragma unroll
            for (int kk = 0; kk < 4; ++kk) {
                pr = MFMA16(ah[kk], Wf[1][1][kk], pr);
                pu = MFMA16(ah[kk], Wf[0][1][kk], pu);
            }
            float uu[4];
            #pragma unroll
            for (int i = 0; i < 4; ++i) {
                float rr = fsig(pr[i]);
                RHb[quad * 4 + i][n] = (bf16)(rr * h[i]);
                uu[i] = fsig(pu[i]);          // off phase-2 critical path
            }
            bar_lgkm();
            // ---- phase 2: c h-part + next step's x-parts as filler ----
            bf16x8 ar[4];
            #pragma unroll
            for (int kk = 0; kk < 4; ++kk)
                ar[kk] = *(const bf16x8*)&RHb[l15][kk * 32 + quad * 8];
            #pragma unroll
            for (int kk = 0; kk < 4; ++kk)
                pc = MFMA16(ar[kk], Wf[2][1][kk], pc);
            f32x4 prN, puN, pcN;
            if (s + 1 < ACHUNK) xparts(buf, s + 1, prN, puN, pcN);
            #pragma unroll
            for (int i = 0; i < 4; ++i) {
                float a  = As[buf][s][quad * 4 + i];
                float cg = ftanh_(pc[i]);
                float ut = uu[i] * a;
                float hn = (1.f - ut) * h[i] + ut * cg;
                h[i] = hn;
                Hb[quad * 4 + i][n] = (bf16)hn;
            }
            if (c + 1 < NCH) commit_part(buf ^ 1, s);   // vmcnt counted here only
            bar_lgkm();
            if (s + 1 < ACHUNK) { pr = prN; pu = puN; pc = pcN; }
        }
        // chunk-boundary peel: x-parts for next chunk's s=0 (buffer fully
        // committed; one barrier between last commit slice and these reads)
        if (c + 1 < NCH) xparts(buf ^ 1, 0, pr, pu, pc);
    }

    // write h_final from lane-private registers
    #pragma unroll
    for (int i = 0; i < 4; ++i)
        OUT[(long)(b0 + quad * 4 + i) * U_SZ + n] = h[i];
}

extern "C" void kernel_launch(void* const* d_in, const int* in_sizes, int n_in,
                              void* d_out, int out_size, void* d_ws, size_t ws_size,
                              hipStream_t stream) {
    const float* X   = (const float*)d_in[0];
    const float* Q   = (const float*)d_in[1];
    const int*   LEN = (const int*)d_in[2];
    const float* W1  = (const float*)d_in[3];
    const float* A1  = (const float*)d_in[4];
    const float* W2  = (const float*)d_in[5];
    const float* A2  = (const float*)d_in[6];
    const float* W3  = (const float*)d_in[7];
    const float* WU  = (const float*)d_in[8];
    const float* WR  = (const float*)d_in[9];
    const float* WC  = (const float*)d_in[10];
    float* OUT = (float*)d_out;

    // workspace layout
    float* ATT  = (float*)d_ws;                       // B*T fp32   (3.28 MB)
    float* BIAS = ATT + (size_t)B_SZ * T_SZ;          // B*64 fp32  (1.05 MB)
    bf16*  W1P  = (bf16*)(BIAS + (size_t)B_SZ * 64);  // 64*256 bf16
    bf16*  W2T  = W1P + 64 * 256;                     // 16*64 bf16

    prep_kernel<<<257, 256, 0, stream>>>(Q, W1, W2, BIAS, W1P, W2T);
    attn_kernel<<<B_SZ / ATTB, 256, 0, stream>>>(X, Q, LEN, A1, A2, W3, BIAS, W1P, W2T, ATT);
    augru_kernel<<<B_SZ / AROWS, 512, 0, stream>>>(X, ATT, WU, WR, WC, OUT);
}

// Round 2
// 809.842 us; speedup vs baseline: 1.0287x; 1.0287x over previous
//
#include <hip/hip_runtime.h>
#include <math.h>

typedef __bf16 bf16;
typedef __bf16 bf16x8 __attribute__((ext_vector_type(8)));
typedef float  f32x4  __attribute__((ext_vector_type(4)));

#define MFMA16(a,b,c) __builtin_amdgcn_mfma_f32_16x16x32_bf16((a),(b),(c),0,0,0)

#define B_SZ 4096
#define T_SZ 200
#define D_SZ 128
#define U_SZ 128
#define ACHUNK 4
#define AROWS 16    // batch rows per block (full M=16 MFMA tiles)

__device__ __forceinline__ float frcp_(float x) { return __builtin_amdgcn_rcpf(x); }
__device__ __forceinline__ float fsig(float x)  { return frcp_(1.0f + __expf(-x)); }
__device__ __forceinline__ float ftanh_(float x){ return 1.0f - 2.0f * frcp_(1.0f + __expf(2.0f * x)); }
// dice with moving_mean=0, moving_var=1: x_norm == x (1/sqrt(1+1e-9) rounds to 1.0f)
__device__ __forceinline__ float dicef(float x, float alpha) {
    float p = fsig(x);
    return alpha * (1.0f - p) * x + p * x;
}
// Barrier that waits ONLY lgkmcnt (LDS visibility). Register-destined global
// loads stay in flight across it. All call sites are wave-uniform.
__device__ __forceinline__ void bar_lgkm() {
    asm volatile("s_waitcnt lgkmcnt(0)\n\ts_barrier" ::: "memory");
}

// ---------------------------------------------------------------------------
// Prep: blocks 0..255 compute bias1[b,n] = q[b]@(W1a+W1c) via MFMA (16 rows each).
// Block 256 converts combined W1' -> bf16 [n][k] (k<128: W1b-W1c; k>=128: W1d)
// and W2^T -> bf16 [n][k].
// ---------------------------------------------------------------------------
__global__ __launch_bounds__(256) void prep_kernel(
    const float* __restrict__ Q,    // [B,128]
    const float* __restrict__ W1,   // [512,64]
    const float* __restrict__ W2,   // [64,16]
    float* __restrict__ BIAS,       // [B,64]
    bf16*  __restrict__ W1P,        // [64][256]
    bf16*  __restrict__ W2T)        // [16][64]
{
    const int tid = threadIdx.x;
    if (blockIdx.x == 256) {
        #pragma unroll 4
        for (int it = 0; it < 64; ++it) {
            int idx = it * 256 + tid;
            int k = idx >> 6;           // 0..255
            int n = idx & 63;
            float v;
            if (k < 128) v = W1[(128 + k) * 64 + n] - W1[(256 + k) * 64 + n];
            else         v = W1[(384 + (k - 128)) * 64 + n];
            W1P[n * 256 + k] = (bf16)v;
        }
        #pragma unroll
        for (int it = 0; it < 4; ++it) {
            int idx = it * 256 + tid; int k = idx >> 4; int n = idx & 15;
            W2T[n * 64 + k] = (bf16)W2[k * 16 + n];
        }
        return;
    }
    const int b0   = blockIdx.x * 16;
    const int lane = tid & 63;
    const int w    = tid >> 6;
    const int quad = lane >> 4;
    const int l15  = lane & 15;

    bf16x8 a[4];
    #pragma unroll
    for (int kk = 0; kk < 4; ++kk) {
        const float* p = Q + (long)(b0 + l15) * D_SZ + kk * 32 + quad * 8;
        float4 x0 = ((const float4*)p)[0];
        float4 x1 = ((const float4*)p)[1];
        float xv[8] = {x0.x, x0.y, x0.z, x0.w, x1.x, x1.y, x1.z, x1.w};
        #pragma unroll
        for (int j = 0; j < 8; ++j) a[kk][j] = (bf16)xv[j];
    }
    const int n = w * 16 + l15;
    f32x4 acc = {};
    #pragma unroll
    for (int kk = 0; kk < 4; ++kk) {
        bf16x8 bf;
        #pragma unroll
        for (int j = 0; j < 8; ++j) {
            int k = kk * 32 + quad * 8 + j;
            bf[j] = (bf16)(W1[k * 64 + n] + W1[(256 + k) * 64 + n]);
        }
        acc = MFMA16(a[kk], bf, acc);
    }
    #pragma unroll
    for (int i = 0; i < 4; ++i)
        BIAS[(long)(b0 + quad * 4 + i) * 64 + n] = acc[i];
}

// ---------------------------------------------------------------------------
// Fused attention + AUGRU scan. X read ONCE. Per chunk c (4 timesteps):
//   - scan steps run the round-1 two-phase structure (lgkm-only barriers,
//     xparts-of-next-step as phase-2 filler, spread commits).
//   - attention h1 for chunk c+1 slice s-1 runs in step s phase-1 (waves 0-3,
//     wave w owns output cols nt=w; B-frags from LDS W1s). Slice 3 in peel.
//   - attention h2/h3/sigmoid for chunk c slice s runs in step s phase-1
//     (wave 4+s), writing As[s]; phase-2 of the same step consumes it.
// All producer->consumer pairs separated by >=1 barrier (see comments).
// ---------------------------------------------------------------------------
__global__ __launch_bounds__(512) void fused_kernel(
    const float* __restrict__ X,    // [B,T,D]
    const float* __restrict__ Q,    // [B,128]
    const int*   __restrict__ LEN,  // [B,1]
    const float* __restrict__ A1,   // [64]
    const float* __restrict__ A2g,  // [16]
    const float* __restrict__ W3g,  // [16,1]
    const float* __restrict__ BIAS, // [B,64]
    const bf16*  __restrict__ W1P,  // [64][256]
    const bf16*  __restrict__ W2T,  // [16][64]
    const float* __restrict__ WU,   // [256,128]
    const float* __restrict__ WR,
    const float* __restrict__ WC,
    float* __restrict__ OUT)        // [B,128]
{
    __shared__ bf16  Xs[2][ACHUNK][16][136];   // 34.8 KB
    __shared__ bf16  XQs[ACHUNK][16][136];     // 17.4 KB (single buffer: see schedule)
    __shared__ bf16  W1s[64 * 264];            // 33.8 KB, pad 264 -> 2-way banks on b128
    __shared__ bf16  Hb[16][136];
    __shared__ bf16  RHb[16][136];
    __shared__ bf16  H1s[ACHUNK * 16 * 72];    // 9.2 KB dice(h1) per slice
    __shared__ float qf[16 * 132];             // fp32 q, pad 132
    __shared__ float bias_s[16 * 68];
    __shared__ float As[ACHUNK * 16];          // attention scores, current chunk
    __shared__ int   lens16[16];

    const int tid  = threadIdx.x;
    const int lane = tid & 63;
    const int w    = tid >> 6;      // 0..7
    const int quad = lane >> 4;
    const int l15  = lane & 15;
    const int b0   = blockIdx.x * AROWS;
    const int n    = w * 16 + l15;  // this lane's augru output column

    // ---- stage block-invariant LDS ----
    for (int idx = tid; idx < 64 * 32; idx += 512) {           // W1P -> W1s
        int nn = idx >> 5, k8 = idx & 31;
        *(bf16x8*)&W1s[nn * 264 + k8 * 8] = *(const bf16x8*)(W1P + nn * 256 + k8 * 8);
    }
    for (int i = tid; i < 16 * 128; i += 512) {
        int r = i >> 7, k = i & 127;
        qf[r * 132 + k] = Q[(long)(b0 + r) * D_SZ + k];
    }
    for (int i = tid; i < 16 * 64; i += 512) {
        int r = i >> 6, c2 = i & 63;
        bias_s[r * 68 + c2] = BIAS[(long)(b0 + r) * 64 + c2];
    }
    if (tid < 16) lens16[tid] = LEN[b0 + tid];
    for (int i = tid; i < 16 * 136; i += 512) { ((bf16*)Hb)[i] = (bf16)0.f; ((bf16*)RHb)[i] = (bf16)0.f; }

    const float al1v = A1[(w & 3) * 16 + l15];
    const float al2v = A2g[l15];
    const float w3v  = W3g[l15];
    bf16x8 b2f[2];
    #pragma unroll
    for (int kk = 0; kk < 2; ++kk)
        b2f[kk] = *(const bf16x8*)(W2T + l15 * 64 + kk * 32 + quad * 8);

    // per-wave augru weight slice: 24 frags = 96 VGPR
    bf16x8 Wf[3][2][4];
    {
        const float* Wg[3] = {WU, WR, WC};
        #pragma unroll
        for (int g = 0; g < 3; ++g)
            #pragma unroll
            for (int p = 0; p < 2; ++p)
                #pragma unroll
                for (int kk = 0; kk < 4; ++kk) {
                    #pragma unroll
                    for (int i = 0; i < 8; ++i) {
                        int k = p * 128 + kk * 32 + quad * 8 + i;
                        Wf[g][p][kk][i] = (bf16)Wg[g][k * 128 + n];
                    }
                }
    }

    float h[4] = {0.f, 0.f, 0.f, 0.f};   // lane-private hidden state

    float4 pf[4];
    auto issue_loads = [&](int c) {
        #pragma unroll
        for (int it = 0; it < 4; ++it) {
            int gidx = it * 512 + tid;
            int c4 = gidx & 31;
            int pair = gidx >> 5;
            int r = pair & 15;
            int s = pair >> 4;
            pf[it] = *(const float4*)(X + ((long)(b0 + r) * T_SZ + (c * ACHUNK + s)) * D_SZ + c4 * 4);
        }
    };
    // commit slice `it` == time-slot `it`; also writes XQs = bf16(x_f32 * q_f32)
    auto commit_part = [&](int bufw, int it) {
        int gidx = it * 512 + tid;
        int c4 = gidx & 31;
        int pair = gidx >> 5;
        int r = pair & 15;
        int sl = pair >> 4;                 // == it
        float4 v = pf[it];
        float4 qv = *(const float4*)&qf[r * 132 + c4 * 4];
        bf16* dx = &Xs[bufw][sl][r][c4 * 4];
        bf16* dq = &XQs[sl][r][c4 * 4];
        dx[0] = (bf16)v.x; dx[1] = (bf16)v.y; dx[2] = (bf16)v.z; dx[3] = (bf16)v.w;
        dq[0] = (bf16)(v.x * qv.x); dq[1] = (bf16)(v.y * qv.y);
        dq[2] = (bf16)(v.z * qv.z); dq[3] = (bf16)(v.w * qv.w);
    };
    // h-independent x-parts of one scan step (12 MFMAs, 3 independent chains)
    auto xparts = [&](int bufw, int s, f32x4& pr_, f32x4& pu_, f32x4& pc_) {
        f32x4 r0 = {}, u0 = {}, c0 = {};
        #pragma unroll
        for (int kk = 0; kk < 4; ++kk) {
            bf16x8 ax = *(const bf16x8*)&Xs[bufw][s][l15][kk * 32 + quad * 8];
            r0 = MFMA16(ax, Wf[1][0][kk], r0);
            u0 = MFMA16(ax, Wf[0][0][kk], u0);
            c0 = MFMA16(ax, Wf[2][0][kk], c0);
        }
        pr_ = r0; pu_ = u0; pc_ = c0;
    };
    // attention h1 for one slice, wave w<4 owns cols nt=w (K=256: ax | aq)
    auto h1f = [&](int bufw, int s) {
        f32x4 acc = {};
        #pragma unroll
        for (int kk = 0; kk < 4; ++kk) {
            bf16x8 ax = *(const bf16x8*)&Xs[bufw][s][l15][kk * 32 + quad * 8];
            bf16x8 bw = *(const bf16x8*)&W1s[n * 264 + kk * 32 + quad * 8];
            acc = MFMA16(ax, bw, acc);
        }
        #pragma unroll
        for (int kk = 0; kk < 4; ++kk) {
            bf16x8 aq = *(const bf16x8*)&XQs[s][l15][kk * 32 + quad * 8];
            bf16x8 bw = *(const bf16x8*)&W1s[n * 264 + 128 + kk * 32 + quad * 8];
            acc = MFMA16(aq, bw, acc);
        }
        #pragma unroll
        for (int i = 0; i < 4; ++i) {
            int row = quad * 4 + i;
            float v = acc[i] + bias_s[row * 68 + n];
            H1s[(s * 16 + row) * 72 + n] = (bf16)dicef(v, al1v);
        }
    };
    // attention h2 @ W2 -> dice -> @W3 -> sigmoid+mask; writes As[s]
    auto h23f = [&](int s, int cc) {
        f32x4 acc2 = {};
        #pragma unroll
        for (int kk = 0; kk < 2; ++kk) {
            bf16x8 a2 = *(const bf16x8*)&H1s[(s * 16 + l15) * 72 + kk * 32 + quad * 8];
            acc2 = MFMA16(a2, b2f[kk], acc2);
        }
        float sv[4];
        #pragma unroll
        for (int i = 0; i < 4; ++i) sv[i] = dicef(acc2[i], al2v) * w3v;
        #pragma unroll
        for (int i = 0; i < 4; ++i) {
            sv[i] += __shfl_xor(sv[i], 1, 64);
            sv[i] += __shfl_xor(sv[i], 2, 64);
            sv[i] += __shfl_xor(sv[i], 4, 64);
            sv[i] += __shfl_xor(sv[i], 8, 64);
        }
        if (l15 == 0) {
            int t = cc * ACHUNK + s;
            #pragma unroll
            for (int i = 0; i < 4; ++i) {
                int row = quad * 4 + i;
                As[s * 16 + row] = (t < lens16[row]) ? fsig(sv[i]) : 0.0f;
            }
        }
    };

    // ---- prologue: chunk 0 staged, its H1s computed ----
    issue_loads(0);
    __syncthreads();                       // staging (qf!) visible before commit
    #pragma unroll
    for (int it = 0; it < 4; ++it) commit_part(0, it);
    bar_lgkm();
    if (w < 4) { h1f(0, 0); h1f(0, 1); h1f(0, 2); h1f(0, 3); }
    bar_lgkm();

    f32x4 pr, pu, pc;
    xparts(0, 0, pr, pu, pc);

    const int NCH = T_SZ / ACHUNK;   // 50
    for (int c = 0; c < NCH; ++c) {
        const int buf  = c & 1;
        const int bufN = buf ^ 1;
        if (c + 1 < NCH) issue_loads(c + 1);   // spans all chunk barriers

        #pragma unroll
        for (int s = 0; s < ACHUNK; ++s) {
            // ---- phase 1: r,u h-parts (critical: pr -> fsig -> RHb) ----
            bf16x8 ah[4];
            #pragma unroll
            for (int kk = 0; kk < 4; ++kk)
                ah[kk] = *(const bf16x8*)&Hb[l15][kk * 32 + quad * 8];
            #pragma unroll
            for (int kk = 0; kk < 4; ++kk) {
                pr = MFMA16(ah[kk], Wf[1][1][kk], pr);
                pu = MFMA16(ah[kk], Wf[0][1][kk], pu);
            }
            float uu[4];
            #pragma unroll
            for (int i = 0; i < 4; ++i) {
                float rr = fsig(pr[i]);
                RHb[quad * 4 + i][n] = (bf16)(rr * h[i]);
                uu[i] = fsig(pu[i]);          // off phase-2 critical path
            }
            // attn filler (after the critical RHb write):
            //  - wave 4+s: h2/h3 for THIS chunk's slice s (H1s written last
            //    chunk / prologue; >=2 barriers ago). As[s] read in phase 2.
            //  - waves 0-3: h1 for NEXT chunk's slice s-1 (committed step s-1
            //    phase 2; 1 barrier ago). Slice 3 handled in the peel.
            if (w >= 4) {
                if (w == 4 + s) h23f(s, c);
            } else if (s >= 1 && c + 1 < NCH) {
                h1f(bufN, s - 1);
            }
            bar_lgkm();
            // ---- phase 2: c h-part + next step's x-parts as filler ----
            bf16x8 ar[4];
            #pragma unroll
            for (int kk = 0; kk < 4; ++kk)
                ar[kk] = *(const bf16x8*)&RHb[l15][kk * 32 + quad * 8];
            #pragma unroll
            for (int kk = 0; kk < 4; ++kk)
                pc = MFMA16(ar[kk], Wf[2][1][kk], pc);
            f32x4 prN, puN, pcN;
            if (s + 1 < ACHUNK) xparts(buf, s + 1, prN, puN, pcN);
            #pragma unroll
            for (int i = 0; i < 4; ++i) {
                float a  = As[s * 16 + quad * 4 + i];
                float cg = ftanh_(pc[i]);
                float ut = uu[i] * a;
                float hn = (1.f - ut) * h[i] + ut * cg;
                h[i] = hn;
                Hb[quad * 4 + i][n] = (bf16)hn;
            }
            if (c + 1 < NCH) commit_part(bufN, s);   // Xs+XQs for chunk c+1
            bar_lgkm();
            if (s + 1 < ACHUNK) { pr = prN; pu = puN; pc = pcN; }
        }
        // peel: next chunk's s=0 x-parts + h1 of its slice 3 (committed in
        // step 3 phase 2; the chunk-final barrier separates write->read)
        if (c + 1 < NCH) {
            xparts(bufN, 0, pr, pu, pc);
            if (w < 4) h1f(bufN, 3);
        }
    }

    // write h_final from lane-private registers
    #pragma unroll
    for (int i = 0; i < 4; ++i)
        OUT[(long)(b0 + quad * 4 + i) * U_SZ + n] = h[i];
}

extern "C" void kernel_launch(void* const* d_in, const int* in_sizes, int n_in,
                              void* d_out, int out_size, void* d_ws, size_t ws_size,
                              hipStream_t stream) {
    const float* X   = (const float*)d_in[0];
    const float* Q   = (const float*)d_in[1];
    const int*   LEN = (const int*)d_in[2];
    const float* W1  = (const float*)d_in[3];
    const float* A1  = (const float*)d_in[4];
    const float* W2  = (const float*)d_in[5];
    const float* A2  = (const float*)d_in[6];
    const float* W3  = (const float*)d_in[7];
    const float* WU  = (const float*)d_in[8];
    const float* WR  = (const float*)d_in[9];
    const float* WC  = (const float*)d_in[10];
    float* OUT = (float*)d_out;

    // workspace layout (ATT eliminated by fusion)
    float* BIAS = (float*)d_ws;                       // B*64 fp32
    bf16*  W1P  = (bf16*)(BIAS + (size_t)B_SZ * 64);  // 64*256 bf16
    bf16*  W2T  = W1P + 64 * 256;                     // 16*64 bf16

    prep_kernel<<<257, 256, 0, stream>>>(Q, W1, W2, BIAS, W1P, W2T);
    fused_kernel<<<B_SZ / AROWS, 512, 0, stream>>>(X, Q, LEN, A1, A2, W3,
                                                   BIAS, W1P, W2T, WU, WR, WC, OUT);
}

// Round 3
// 715.356 us; speedup vs baseline: 1.1646x; 1.1321x over previous
//
#include <hip/hip_runtime.h>
#include <math.h>

typedef __bf16 bf16;
typedef __bf16 bf16x8 __attribute__((ext_vector_type(8)));
typedef float  f32x4  __attribute__((ext_vector_type(4)));

#define MFMA16(a,b,c) __builtin_amdgcn_mfma_f32_16x16x32_bf16((a),(b),(c),0,0,0)

#define B_SZ 4096
#define T_SZ 200
#define D_SZ 128
#define U_SZ 128
#define ACHUNK 4
#define AROWS 16
#define NCH (T_SZ / ACHUNK)   // 50

__device__ __forceinline__ float frcp_(float x) { return __builtin_amdgcn_rcpf(x); }
__device__ __forceinline__ float fsig(float x)  { return frcp_(1.0f + __expf(-x)); }
__device__ __forceinline__ float ftanh_(float x){ return 1.0f - 2.0f * frcp_(1.0f + __expf(2.0f * x)); }
__device__ __forceinline__ float dicef(float x, float alpha) {
    float p = fsig(x);
    return alpha * (1.0f - p) * x + p * x;
}
// Barrier waiting ONLY lgkmcnt (LDS visibility); global loads stay in flight.
__device__ __forceinline__ void bar_lgkm() {
    asm volatile("s_waitcnt lgkmcnt(0)\n\ts_barrier" ::: "memory");
}

// ---------------------------------------------------------------------------
// Prep (unchanged): bias1 = q@(W1a+W1c); W1' -> bf16 [n][256]; W2^T -> bf16.
// ---------------------------------------------------------------------------
__global__ __launch_bounds__(256) void prep_kernel(
    const float* __restrict__ Q,    // [B,128]
    const float* __restrict__ W1,   // [512,64]
    const float* __restrict__ W2,   // [64,16]
    float* __restrict__ BIAS,       // [B,64]
    bf16*  __restrict__ W1P,        // [64][256]
    bf16*  __restrict__ W2T)        // [16][64]
{
    const int tid = threadIdx.x;
    if (blockIdx.x == 256) {
        #pragma unroll 4
        for (int it = 0; it < 64; ++it) {
            int idx = it * 256 + tid;
            int k = idx >> 6;
            int n = idx & 63;
            float v;
            if (k < 128) v = W1[(128 + k) * 64 + n] - W1[(256 + k) * 64 + n];
            else         v = W1[(384 + (k - 128)) * 64 + n];
            W1P[n * 256 + k] = (bf16)v;
        }
        #pragma unroll
        for (int it = 0; it < 4; ++it) {
            int idx = it * 256 + tid; int k = idx >> 4; int n = idx & 15;
            W2T[n * 64 + k] = (bf16)W2[k * 16 + n];
        }
        return;
    }
    const int b0   = blockIdx.x * 16;
    const int lane = tid & 63;
    const int w    = tid >> 6;
    const int quad = lane >> 4;
    const int l15  = lane & 15;

    bf16x8 a[4];
    #pragma unroll
    for (int kk = 0; kk < 4; ++kk) {
        const float* p = Q + (long)(b0 + l15) * D_SZ + kk * 32 + quad * 8;
        float4 x0 = ((const float4*)p)[0];
        float4 x1 = ((const float4*)p)[1];
        float xv[8] = {x0.x, x0.y, x0.z, x0.w, x1.x, x1.y, x1.z, x1.w};
        #pragma unroll
        for (int j = 0; j < 8; ++j) a[kk][j] = (bf16)xv[j];
    }
    const int n = w * 16 + l15;
    f32x4 acc = {};
    #pragma unroll
    for (int kk = 0; kk < 4; ++kk) {
        bf16x8 bf;
        #pragma unroll
        for (int j = 0; j < 8; ++j) {
            int k = kk * 32 + quad * 8 + j;
            bf[j] = (bf16)(W1[k * 64 + n] + W1[(256 + k) * 64 + n]);
        }
        acc = MFMA16(a[kk], bf, acc);
    }
    #pragma unroll
    for (int i = 0; i < 4; ++i)
        BIAS[(long)(b0 + quad * 4 + i) * 64 + n] = acc[i];
}

// ---------------------------------------------------------------------------
// Fused kernel, producer/consumer wave specialization. 768 threads = 12 waves
// (3 waves/SIMD). Waves 0-7: lean AUGRU scan (Wf in regs, 2 phases/step).
// Waves 8-11: producer wave pw owns slice pw of every chunk — loads X (2
// chunks ahead), converts/stages Xs (1 chunk ahead, b128 stores), computes
// attention h1 (32 MFMA) + h23 -> As (double-buffered). Separate branches =
// separate register pressure; barrier ledger matches exactly: 1 + 8*NCH.
// ---------------------------------------------------------------------------
__global__ __launch_bounds__(768, 3) void fused_kernel(
    const float* __restrict__ X,    // [B,T,D]
    const float* __restrict__ Q,    // [B,128]
    const int*   __restrict__ LEN,  // [B,1]
    const float* __restrict__ A1,   // [64]
    const float* __restrict__ A2g,  // [16]
    const float* __restrict__ W3g,  // [16,1]
    const float* __restrict__ BIAS, // [B,64]
    const bf16*  __restrict__ W1P,  // [64][256]
    const bf16*  __restrict__ W2T,  // [16][64]
    const float* __restrict__ WU,   // [256,128]
    const float* __restrict__ WR,
    const float* __restrict__ WC,
    float* __restrict__ OUT)        // [B,128]
{
    __shared__ bf16  Xs[2][ACHUNK][16][136];   // 34.8 KB
    __shared__ bf16  Hb[16][136];
    __shared__ bf16  RHb[16][136];
    __shared__ bf16  H1p[4][16][72];           // per-producer dice(h1) scratch
    __shared__ bf16  W1s[64][264];             // 33.8 KB
    __shared__ float qf[16][132];
    __shared__ float bias_s[16][68];
    __shared__ float As[2][64];                // double-buffered attn scores
    __shared__ int   lens16[16];

    const int tid  = threadIdx.x;
    const int lane = tid & 63;
    const int w    = tid >> 6;      // 0..11
    const int quad = lane >> 4;
    const int l15  = lane & 15;
    const int b0   = blockIdx.x * AROWS;

    // ---- cooperative staging (all 12 waves) ----
    for (int idx = tid; idx < 64 * 32; idx += 768) {
        int nn = idx >> 5, k8 = idx & 31;
        *(bf16x8*)&W1s[nn][k8 * 8] = *(const bf16x8*)(W1P + nn * 256 + k8 * 8);
    }
    for (int i = tid; i < 16 * 128; i += 768) {
        int r = i >> 7, k = i & 127;
        qf[r][k] = Q[(long)(b0 + r) * D_SZ + k];
    }
    for (int i = tid; i < 16 * 64; i += 768) {
        int r = i >> 6, cc = i & 63;
        bias_s[r][cc] = BIAS[(long)(b0 + r) * 64 + cc];
    }
    if (tid < 16) lens16[tid] = LEN[b0 + tid];
    for (int i = tid; i < 16 * 136; i += 768) {
        ((bf16*)Hb)[i] = (bf16)0.f; ((bf16*)RHb)[i] = (bf16)0.f;
    }
    __syncthreads();

    if (w < 8) {
        // ================= SCAN branch (waves 0-7) =================
        const int n = w * 16 + l15;            // output column
        bf16x8 Wf[3][2][4];                    // 96 VGPR
        {
            const float* Wg[3] = {WU, WR, WC};
            #pragma unroll
            for (int g = 0; g < 3; ++g)
                #pragma unroll
                for (int p = 0; p < 2; ++p)
                    #pragma unroll
                    for (int kk = 0; kk < 4; ++kk) {
                        #pragma unroll
                        for (int i = 0; i < 8; ++i) {
                            int k = p * 128 + kk * 32 + quad * 8 + i;
                            Wf[g][p][kk][i] = (bf16)Wg[g][k * 128 + n];
                        }
                    }
        }
        float h[4] = {0.f, 0.f, 0.f, 0.f};
        f32x4 pr, pu, pc;
        auto xparts = [&](int bufw, int s) {
            f32x4 r0 = {}, u0 = {}, c0 = {};
            __builtin_amdgcn_s_setprio(1);
            #pragma unroll
            for (int kk = 0; kk < 4; ++kk) {
                bf16x8 ax = *(const bf16x8*)&Xs[bufw][s][l15][kk * 32 + quad * 8];
                r0 = MFMA16(ax, Wf[1][0][kk], r0);
                u0 = MFMA16(ax, Wf[0][0][kk], u0);
                c0 = MFMA16(ax, Wf[2][0][kk], c0);
            }
            __builtin_amdgcn_s_setprio(0);
            pr = r0; pu = u0; pc = c0;
        };

        bar_lgkm();                  // bar#0: producer prologue done (Xs[0], As[0])
        xparts(0, 0);

        for (int c = 0; c < NCH; ++c) {
            const int buf  = c & 1;
            const int bufN = buf ^ 1;
            #pragma unroll
            for (int s = 0; s < ACHUNK; ++s) {
                // ---- phase 1: r,u h-parts ----
                bf16x8 ah[4];
                #pragma unroll
                for (int kk = 0; kk < 4; ++kk)
                    ah[kk] = *(const bf16x8*)&Hb[l15][kk * 32 + quad * 8];
                __builtin_amdgcn_s_setprio(1);
                #pragma unroll
                for (int kk = 0; kk < 4; ++kk) {
                    pr = MFMA16(ah[kk], Wf[1][1][kk], pr);
                    pu = MFMA16(ah[kk], Wf[0][1][kk], pu);
                }
                __builtin_amdgcn_s_setprio(0);
                float uu[4];
                #pragma unroll
                for (int i = 0; i < 4; ++i) {
                    float rr = fsig(pr[i]);
                    RHb[quad * 4 + i][n] = (bf16)(rr * h[i]);
                    uu[i] = fsig(pu[i]);
                }
                bar_lgkm();
                // ---- phase 2: c h-part, update, next-step xparts ----
                bf16x8 ar[4];
                #pragma unroll
                for (int kk = 0; kk < 4; ++kk)
                    ar[kk] = *(const bf16x8*)&RHb[l15][kk * 32 + quad * 8];
                __builtin_amdgcn_s_setprio(1);
                #pragma unroll
                for (int kk = 0; kk < 4; ++kk)
                    pc = MFMA16(ar[kk], Wf[2][1][kk], pc);
                __builtin_amdgcn_s_setprio(0);
                #pragma unroll
                for (int i = 0; i < 4; ++i) {
                    float a  = As[buf][s * 16 + quad * 4 + i];
                    float cg = ftanh_(pc[i]);
                    float ut = uu[i] * a;
                    float hn = (1.f - ut) * h[i] + ut * cg;
                    h[i] = hn;
                    Hb[quad * 4 + i][n] = (bf16)hn;
                }
                if (s + 1 < ACHUNK)      xparts(buf, s + 1);
                else if (c + 1 < NCH)    xparts(bufN, 0);   // Xs[bufN][0] written slot A0
                bar_lgkm();
            }
        }
        #pragma unroll
        for (int i = 0; i < 4; ++i)
            OUT[(long)(b0 + quad * 4 + i) * U_SZ + n] = h[i];
    } else {
        // ================= PRODUCER branch (waves 8-11) =================
        const int pw = w - 8;                  // owned slice (0..3)
        float al1r[4];
        #pragma unroll
        for (int nt = 0; nt < 4; ++nt) al1r[nt] = A1[nt * 16 + l15];
        const float al2v = A2g[l15];
        const float w3v  = W3g[l15];
        bf16x8 b2f[2];
        #pragma unroll
        for (int kk = 0; kk < 2; ++kk)
            b2f[kk] = *(const bf16x8*)(W2T + l15 * 64 + kk * 32 + quad * 8);

        float4 pf[8];
        bf16x8 axp[4], aqp[4];

        auto p_issue = [&](int cn) {          // load slice pw of chunk cn
            const float* xp = X + ((long)(b0 + l15) * T_SZ + cn * ACHUNK + pw) * D_SZ;
            #pragma unroll
            for (int kk = 0; kk < 4; ++kk) {
                const float* p = xp + kk * 32 + quad * 8;
                pf[kk * 2]     = ((const float4*)p)[0];
                pf[kk * 2 + 1] = ((const float4*)p)[1];
            }
        };
        auto p_convert = [&]() {              // pf -> axp (bf16 x), aqp (bf16 x*q)
            #pragma unroll
            for (int kk = 0; kk < 4; ++kk) {
                float4 xa = pf[kk * 2], xb = pf[kk * 2 + 1];
                float xv[8] = {xa.x, xa.y, xa.z, xa.w, xb.x, xb.y, xb.z, xb.w};
                const float* qp = &qf[l15][kk * 32 + quad * 8];
                #pragma unroll
                for (int j = 0; j < 8; ++j) {
                    axp[kk][j] = (bf16)xv[j];
                    aqp[kk][j] = (bf16)(xv[j] * qp[j]);
                }
            }
        };
        auto p_writeXs = [&](int xb) {        // b128 stores, conflict-free
            #pragma unroll
            for (int kk = 0; kk < 4; ++kk)
                *(bf16x8*)&Xs[xb][pw][l15][kk * 32 + quad * 8] = axp[kk];
        };
        auto p_h1 = [&](int nt) {             // one 16x16 tile of h1, K=256
            f32x4 acc = {};
            #pragma unroll
            for (int kk = 0; kk < 4; ++kk) {
                bf16x8 bw = *(const bf16x8*)&W1s[nt * 16 + l15][kk * 32 + quad * 8];
                acc = MFMA16(axp[kk], bw, acc);
            }
            #pragma unroll
            for (int kk = 0; kk < 4; ++kk) {
                bf16x8 bw = *(const bf16x8*)&W1s[nt * 16 + l15][128 + kk * 32 + quad * 8];
                acc = MFMA16(aqp[kk], bw, acc);
            }
            #pragma unroll
            for (int i = 0; i < 4; ++i) {
                int row = quad * 4 + i;
                float v = acc[i] + bias_s[row][nt * 16 + l15];
                H1p[pw][row][nt * 16 + l15] = (bf16)dicef(v, al1r[nt]);
            }
        };
        auto p_h23 = [&](int cn, int ab) {    // h2/h3/sigmoid -> As[ab]
            f32x4 acc2 = {};
            #pragma unroll
            for (int kk = 0; kk < 2; ++kk) {
                bf16x8 a2 = *(const bf16x8*)&H1p[pw][l15][kk * 32 + quad * 8];
                acc2 = MFMA16(a2, b2f[kk], acc2);
            }
            float sv[4];
            #pragma unroll
            for (int i = 0; i < 4; ++i) sv[i] = dicef(acc2[i], al2v) * w3v;
            #pragma unroll
            for (int i = 0; i < 4; ++i) {
                sv[i] += __shfl_xor(sv[i], 1, 64);
                sv[i] += __shfl_xor(sv[i], 2, 64);
                sv[i] += __shfl_xor(sv[i], 4, 64);
                sv[i] += __shfl_xor(sv[i], 8, 64);
            }
            if (l15 == 0) {
                int t = cn * ACHUNK + pw;
                #pragma unroll
                for (int i = 0; i < 4; ++i) {
                    int row = quad * 4 + i;
                    As[ab][pw * 16 + row] = (t < lens16[row]) ? fsig(sv[i]) : 0.0f;
                }
            }
        };

        // ---- prologue: fully prepare chunk 0; prime loads for chunk 1 ----
        p_issue(0);
        p_convert();
        p_writeXs(0);
        p_h1(0); p_h1(1); p_h1(2); p_h1(3);
        p_h23(0, 0);
        if (NCH > 1) p_issue(1);
        bar_lgkm();                  // bar#0

        // ---- main loop: during chunk c, prepare chunk cn=c+1; load c+2 ----
        for (int c = 0; c < NCH; ++c) {
            const int cn = c + 1;
            const int xb = cn & 1;
            const bool act = cn < NCH;
            // slot A0
            if (act) { p_convert(); p_writeXs(xb); }
            bar_lgkm();
            // slot B0
            if (c + 2 < NCH) p_issue(c + 2);
            bar_lgkm();
            // slot A1
            if (act) p_h1(0);
            bar_lgkm();
            // slot B1
            if (act) p_h1(1);
            bar_lgkm();
            // slot A2
            if (act) p_h1(2);
            bar_lgkm();
            // slot B2
            if (act) p_h1(3);
            bar_lgkm();
            // slot A3
            if (act) p_h23(cn, xb);
            bar_lgkm();
            // slot B3 (slack)
            bar_lgkm();
        }
    }
}

extern "C" void kernel_launch(void* const* d_in, const int* in_sizes, int n_in,
                              void* d_out, int out_size, void* d_ws, size_t ws_size,
                              hipStream_t stream) {
    const float* X   = (const float*)d_in[0];
    const float* Q   = (const float*)d_in[1];
    const int*   LEN = (const int*)d_in[2];
    const float* W1  = (const float*)d_in[3];
    const float* A1  = (const float*)d_in[4];
    const float* W2  = (const float*)d_in[5];
    const float* A2  = (const float*)d_in[6];
    const float* W3  = (const float*)d_in[7];
    const float* WU  = (const float*)d_in[8];
    const float* WR  = (const float*)d_in[9];
    const float* WC  = (const float*)d_in[10];
    float* OUT = (float*)d_out;

    float* BIAS = (float*)d_ws;                       // B*64 fp32
    bf16*  W1P  = (bf16*)(BIAS + (size_t)B_SZ * 64);  // 64*256 bf16
    bf16*  W2T  = W1P + 64 * 256;                     // 16*64 bf16

    prep_kernel<<<257, 256, 0, stream>>>(Q, W1, W2, BIAS, W1P, W2T);
    fused_kernel<<<B_SZ / AROWS, 768, 0, stream>>>(X, Q, LEN, A1, A2, W3,
                                                   BIAS, W1P, W2T, WU, WR, WC, OUT);
}